// Round 5
// baseline (6765.643 us; speedup 1.0000x reference)
//
#include <hip/hip_runtime.h>
#include <hip/hip_bf16.h>

#define S 2048
#define HD 512
#define EDIM 512
#define NT 12
#define G4 2048            // 4*HD gate rows
#define NWGD 16            // workgroups per direction
#define UPW 32             // hidden units per WG
#define XROW 72            // xstage row stride (ushorts): 144B, 16B-aligned, bank-spread

typedef unsigned short ushort_t;
typedef unsigned int uint_t;

__device__ __forceinline__ ushort_t f2b(float f) {
    uint_t u = __float_as_uint(f);
    uint_t r = u + 0x7fffu + ((u >> 16) & 1u);
    return (ushort_t)(r >> 16);
}
__device__ __forceinline__ float b2f(ushort_t h) {
    return __uint_as_float(((uint_t)h) << 16);
}
__device__ __forceinline__ float sigm(float x) { return 1.f / (1.f + __expf(-x)); }
__device__ __forceinline__ float tanh_(float x) {
    float e = __expf(2.f * x);
    return 1.f - 2.f / (e + 1.f);
}

// ---------------- xw GEMM: xwT[d][r][t] = emb[tok(d,t)] . wih_d[r] + b_d[r] (TRANSPOSED out) ----
__global__ __launch_bounds__(256, 2)
void xw_gemm(const int* __restrict__ sentence, const float* __restrict__ emb,
             const float* __restrict__ wih_f, const float* __restrict__ b_f,
             const float* __restrict__ wih_b, const float* __restrict__ b_b,
             ushort_t* __restrict__ xwT) {
    __shared__ float As[32][68];
    __shared__ float Bs[32][68];
    __shared__ int toks[64];
    const int tid = threadIdx.x;
    const int tbase = blockIdx.x * 64;
    const int rbase = blockIdx.y * 64;
    const int dir = blockIdx.z;
    const float* wih = dir ? wih_b : wih_f;
    const float* bia = dir ? b_b : b_f;
    if (tid < 64) {
        int tt = tbase + tid;
        toks[tid] = sentence[dir ? (S - 1 - tt) : tt];
    }
    __syncthreads();
    const int lm = tid >> 2;
    const int lk = (tid & 3) * 8;
    const int ty = tid >> 4, tx = tid & 15;
    const float* aBase = emb + (size_t)toks[lm] * EDIM + lk;
    const float* bBase = wih + (size_t)(rbase + lm) * EDIM + lk;
    float acc[4][4];
#pragma unroll
    for (int i = 0; i < 4; ++i)
#pragma unroll
        for (int j = 0; j < 4; ++j) acc[i][j] = 0.f;

    for (int kcc = 0; kcc < EDIM; kcc += 32) {
        float4 a0 = ((const float4*)(aBase + kcc))[0];
        float4 a1 = ((const float4*)(aBase + kcc))[1];
        float4 b0 = ((const float4*)(bBase + kcc))[0];
        float4 b1 = ((const float4*)(bBase + kcc))[1];
        __syncthreads();
        As[lk + 0][lm] = a0.x; As[lk + 1][lm] = a0.y; As[lk + 2][lm] = a0.z; As[lk + 3][lm] = a0.w;
        As[lk + 4][lm] = a1.x; As[lk + 5][lm] = a1.y; As[lk + 6][lm] = a1.z; As[lk + 7][lm] = a1.w;
        Bs[lk + 0][lm] = b0.x; Bs[lk + 1][lm] = b0.y; Bs[lk + 2][lm] = b0.z; Bs[lk + 3][lm] = b0.w;
        Bs[lk + 4][lm] = b1.x; Bs[lk + 5][lm] = b1.y; Bs[lk + 6][lm] = b1.z; Bs[lk + 7][lm] = b1.w;
        __syncthreads();
#pragma unroll
        for (int kk = 0; kk < 32; ++kk) {
            float4 a4 = *(const float4*)&As[kk][ty * 4];
            float4 b4 = *(const float4*)&Bs[kk][tx * 4];
            float av[4] = {a4.x, a4.y, a4.z, a4.w};
            float bv[4] = {b4.x, b4.y, b4.z, b4.w};
#pragma unroll
            for (int i = 0; i < 4; ++i)
#pragma unroll
                for (int j = 0; j < 4; ++j) acc[i][j] = fmaf(av[i], bv[j], acc[i][j]);
        }
    }
    float4 bi = *(const float4*)&bia[rbase + tx * 4];
    float bvv[4] = {bi.x, bi.y, bi.z, bi.w};
    // transposed epilogue: row-major [row][t]
#pragma unroll
    for (int j = 0; j < 4; ++j) {
        ushort4 o;
        o.x = f2b(acc[0][j] + bvv[j]);
        o.y = f2b(acc[1][j] + bvv[j]);
        o.z = f2b(acc[2][j] + bvv[j]);
        o.w = f2b(acc[3][j] + bvv[j]);
        ushort_t* p = xwT + ((size_t)dir * G4 + rbase + tx * 4 + j) * S + tbase + ty * 4;
        *(ushort4*)p = o;
    }
}

// ---------------- LSTM recurrence: 32 WGs x 512 thr, in-wave gates, 1 barrier/step --------
// Lane layout (per wave): r=lane>>2 (16 rows), kc=lane&3 (128-k chunk). Row r -> gate=r&3,
// unit u = wv*4 + (r>>2). Weights f32 reg-stationary (128 VGPR). h double-buffered in LDS;
// consumers value-canary-poll hs directly (256 lanes x 1 u64 slot).
__global__ __launch_bounds__(512, 2)
void lstm_rec(const float* __restrict__ whh_f, const float* __restrict__ whh_b,
              const float* __restrict__ h0, const float* __restrict__ c0,
              const ushort_t* __restrict__ xwT, float* hs) {
    __shared__ float hstage[2][544];            // 4 chunks x 136 dwords (bank-spread)
    __shared__ ushort_t xstage[2][128 * XROW];  // dbuf 64-step xw chunk, padded rows
    const int tid = threadIdx.x;
    const int wv = tid >> 6;
    const int lane = tid & 63;
    const int dir = blockIdx.x >> 4;
    const int wg = blockIdx.x & 15;
    const int jbase = wg * UPW;
    const int kc = lane & 3;
    const int gate = (lane >> 2) & 3;
    const int ju = lane >> 4;                   // 0..3
    const int u = wv * 4 + ju;                  // WG-local unit 0..31
    const int grow = gate * HD + jbase + u;
    const float* whh = dir ? whh_b : whh_f;

    // register-stationary weights: 128 f32 (32 float4) per lane
    float4 w[32];
#pragma unroll
    for (int i = 0; i < 32; ++i)
        w[i] = *(const float4*)&whh[(size_t)grow * HD + kc * 128 + i * 4];

    const ushort_t* xwd = xwT + (size_t)dir * G4 * S;
    float* hsd = hs + (size_t)dir * S * HD;

    // xw staging: 128 rows x 64 t per chunk; 2 passes of 64 rows (8 lanes x 16B per row)
    const int ri0 = tid >> 3;
    const int ri1 = ri0 + 64;
    const int off = (tid & 7) * 8;
    const ushort_t* sb0 = xwd + (size_t)((ri0 >> 5) * HD + jbase + (ri0 & 31)) * S;
    const ushort_t* sb1 = xwd + (size_t)((ri1 >> 5) * HD + jbase + (ri1 & 31)) * S;
    *(uint4*)&xstage[0][ri0 * XROW + off] = *(const uint4*)(sb0 + off);
    *(uint4*)&xstage[0][ri1 * XROW + off] = *(const uint4*)(sb1 + off);

    const bool upd = (lane & 15) == 0;
    float cj = upd ? c0[dir * HD + jbase + u] : 0.f;

    // stage h0 into buf 1 (matvec t reads buf (t+1)&1)
    if (tid < 256) {
        float2 v = *(const float2*)&h0[dir * HD + 2 * tid];
        int p = 2 * tid;
        *(float2*)&hstage[1][(p >> 7) * 136 + (p & 127)] = v;
    }
    __syncthreads();

    const int sbase = lane & 48;                // ju*16: lanes holding this unit's 4 gate sums
    for (int t = 0; t < S; ++t) {
        if ((t & 63) == 0 && t + 64 < S) {      // prefetch next xw chunk
            int nb = ((t >> 6) + 1) & 1;
            *(uint4*)&xstage[nb][ri0 * XROW + off] = *(const uint4*)(sb0 + t + 64 + off);
            *(uint4*)&xstage[nb][ri1 * XROW + off] = *(const uint4*)(sb1 + t + 64 + off);
        }
        const float* hb = &hstage[(t + 1) & 1][kc * 136];
        float4 a4 = {0.f, 0.f, 0.f, 0.f};
#pragma unroll
        for (int i = 0; i < 32; ++i) {
            float4 h4 = *(const float4*)&hb[i * 4];
            a4.x = fmaf(w[i].x, h4.x, a4.x);
            a4.y = fmaf(w[i].y, h4.y, a4.y);
            a4.z = fmaf(w[i].z, h4.z, a4.z);
            a4.w = fmaf(w[i].w, h4.w, a4.w);
        }
        float acc = (a4.x + a4.y) + (a4.z + a4.w);
        acc += __shfl_xor(acc, 1);
        acc += __shfl_xor(acc, 2);
        float g0 = __shfl(acc, sbase);
        float g1 = __shfl(acc, sbase + 4);
        float g2 = __shfl(acc, sbase + 8);
        float g3 = __shfl(acc, sbase + 12);
        if (upd) {
            int tt = t & 63;
            int xb = (t >> 6) & 1;
            float gi = g0 + b2f(xstage[xb][(0 * 32 + u) * XROW + tt]);
            float gf = g1 + b2f(xstage[xb][(1 * 32 + u) * XROW + tt]);
            float gg = g2 + b2f(xstage[xb][(2 * 32 + u) * XROW + tt]);
            float go = g3 + b2f(xstage[xb][(3 * 32 + u) * XROW + tt]);
            float ii = sigm(gi), ff = sigm(gf), gv = tanh_(gg), oo = sigm(go);
            cj = ff * cj + ii * gv;
            float hnew = oo * tanh_(cj);
            __hip_atomic_store(&hsd[(size_t)t * HD + jbase + u], hnew,
                               __ATOMIC_RELAXED, __HIP_MEMORY_SCOPE_AGENT);
        }
        if (t < S - 1 && tid < 256) {
            // value-canary poll: lane covers u64 slot tid (h[2*tid], h[2*tid+1])
            const unsigned long long* pb =
                (const unsigned long long*)&hsd[(size_t)t * HD] + tid;
            unsigned long long v;
            for (;;) {
                v = __hip_atomic_load(pb, __ATOMIC_RELAXED, __HIP_MEMORY_SCOPE_AGENT);
                if ((uint_t)v != 0xFFFFFFFFu && (uint_t)(v >> 32) != 0xFFFFFFFFu) break;
            }
            int p = 2 * tid;
            *(unsigned long long*)&hstage[t & 1][(p >> 7) * 136 + (p & 127)] = v;
        }
        __syncthreads();
    }
}

// ---------------- feats: [S][12] = concat(hf, hb_rev) @ w_out.T + b_out ----------------
__global__ __launch_bounds__(256)
void feats_k(const float* __restrict__ hs, const float* __restrict__ w_out,
             const float* __restrict__ b_out, float* __restrict__ feats) {
    const int t = blockIdx.x, tid = threadIdx.x;
    float4 h4;
    if (tid < 128)
        h4 = *(const float4*)&hs[(size_t)t * HD + tid * 4];
    else
        h4 = *(const float4*)&hs[(size_t)S * HD + (size_t)(S - 1 - t) * HD + (tid - 128) * 4];
    float acc[NT];
#pragma unroll
    for (int tg = 0; tg < NT; ++tg) {
        float4 w4 = *(const float4*)&w_out[(size_t)tg * 1024 + tid * 4];
        acc[tg] = h4.x * w4.x + h4.y * w4.y + h4.z * w4.z + h4.w * w4.w;
    }
#pragma unroll
    for (int m = 1; m < 64; m <<= 1)
#pragma unroll
        for (int tg = 0; tg < NT; ++tg) acc[tg] += __shfl_xor(acc[tg], m);
    __shared__ float part[4][NT];
    if ((tid & 63) == 0) {
#pragma unroll
        for (int tg = 0; tg < NT; ++tg) part[tid >> 6][tg] = acc[tg];
    }
    __syncthreads();
    if (tid < NT)
        feats[(size_t)t * NT + tid] =
            part[0][tid] + part[1][tid] + part[2][tid] + part[3][tid] + b_out[tid];
}

// ---------------- CRF: forward algorithm + gold score, single block ----------------
__global__ __launch_bounds__(256, 1)
void crf_k(const float* __restrict__ feats, const int* __restrict__ gold,
           const float* __restrict__ trans, float* __restrict__ out) {
    extern __shared__ float sfeats[];      // S*NT floats = 96KB
    __shared__ float red[256];
    __shared__ float nprev[NT];
    __shared__ float tr[144];
    __shared__ float gold_sh;
    const int tid = threadIdx.x;
    for (int i = tid; i < S * NT / 4; i += 256)
        ((float4*)sfeats)[i] = ((const float4*)feats)[i];
    if (tid < 144) tr[tid] = trans[tid];
    __syncthreads();
    // gold score
    float gsum = 0.f;
    for (int t = tid; t < S; t += 256) {
        int a = gold[t];
        int b = t ? gold[t - 1] : 0;
        gsum += tr[a * NT + b] + sfeats[t * NT + a];
    }
    red[tid] = gsum;
    __syncthreads();
    for (int s = 128; s; s >>= 1) {
        if (tid < s) red[tid] += red[tid + s];
        __syncthreads();
    }
    if (tid == 0) gold_sh = red[0] + tr[1 * NT + gold[S - 1]];
    __syncthreads();
    // forward algorithm: i = tid/16 (next tag), j = tid%16 (prev tag)
    const int i = tid >> 4, j = tid & 15;
    const bool act = (tid < 192) && (j < NT);
    float tij = act ? tr[i * NT + j] : -3e38f;
    float prev = (j == 0) ? 0.f : -1e6f;
    for (int t = 0; t < S; ++t) {
        float v = act ? (prev + tij) : -3e38f;
        float mx = v;
        mx = fmaxf(mx, __shfl_xor(mx, 1));
        mx = fmaxf(mx, __shfl_xor(mx, 2));
        mx = fmaxf(mx, __shfl_xor(mx, 4));
        mx = fmaxf(mx, __shfl_xor(mx, 8));
        float e = __expf(v - mx);
        float ss = e;
        ss += __shfl_xor(ss, 1);
        ss += __shfl_xor(ss, 2);
        ss += __shfl_xor(ss, 4);
        ss += __shfl_xor(ss, 8);
        if (tid < 192 && j == 0) nprev[i] = mx + __logf(ss) + sfeats[t * NT + i];
        __syncthreads();
        prev = nprev[j < NT ? j : 0];
        __syncthreads();
    }
    if (tid < 64) {
        float v2 = (tid < NT) ? prev + tr[1 * NT + tid] : -3e38f;
        float mx = v2;
        mx = fmaxf(mx, __shfl_xor(mx, 1));
        mx = fmaxf(mx, __shfl_xor(mx, 2));
        mx = fmaxf(mx, __shfl_xor(mx, 4));
        mx = fmaxf(mx, __shfl_xor(mx, 8));
        float e = __expf(v2 - mx);
        float ss = e;
        ss += __shfl_xor(ss, 1);
        ss += __shfl_xor(ss, 2);
        ss += __shfl_xor(ss, 4);
        ss += __shfl_xor(ss, 8);
        if (tid == 0) out[0] = (mx + __logf(ss)) - gold_sh;
    }
}

extern "C" void kernel_launch(void* const* d_in, const int* in_sizes, int n_in,
                              void* d_out, int out_size, void* d_ws, size_t ws_size,
                              hipStream_t stream) {
    const int* sentence = (const int*)d_in[0];
    const int* gold = (const int*)d_in[1];
    const float* emb = (const float*)d_in[2];
    const float* wih_f = (const float*)d_in[3];
    const float* whh_f = (const float*)d_in[4];
    const float* b_f = (const float*)d_in[5];
    const float* wih_b = (const float*)d_in[6];
    const float* whh_b = (const float*)d_in[7];
    const float* b_b = (const float*)d_in[8];
    const float* w_out = (const float*)d_in[9];
    const float* b_out = (const float*)d_in[10];
    const float* trans = (const float*)d_in[11];
    const float* h0 = (const float*)d_in[12];
    const float* c0 = (const float*)d_in[13];
    float* out = (float*)d_out;

    char* ws = (char*)d_ws;
    const size_t XW_B = (size_t)2 * S * G4 * 2;          // 16,777,216
    const size_t HS_B = (size_t)2 * S * HD * 4;          // 8,388,608
    ushort_t* xwT = (ushort_t*)ws;
    float* hs = (float*)(ws + XW_B);
    float* feats = (float*)(ws + XW_B + HS_B);

    // canary-fill h state buffer (0xFFFFFFFF, impossible output value)
    hipMemsetAsync(hs, 0xFF, HS_B, stream);

    dim3 gg(S / 64, G4 / 64, 2);
    xw_gemm<<<gg, 256, 0, stream>>>(sentence, emb, wih_f, b_f, wih_b, b_b, xwT);

    lstm_rec<<<2 * NWGD, 512, 0, stream>>>(whh_f, whh_b, h0, c0, xwT, hs);

    feats_k<<<S, 256, 0, stream>>>(hs, w_out, b_out, feats);

    const size_t CRF_LDS = (size_t)S * NT * 4;           // 98,304 B
    hipFuncSetAttribute((const void*)crf_k,
                        hipFuncAttributeMaxDynamicSharedMemorySize, (int)CRF_LDS);
    crf_k<<<1, 256, CRF_LDS, stream>>>(feats, gold, trans, out);
}